// Round 5
// baseline (171.803 us; speedup 1.0000x reference)
//
#include <hip/hip_runtime.h>

#define BB 4
#define NN 2048
#define INF 256
#define HH 8
#define DD 32
#define LOG2E 1.4426950408889634f

typedef __attribute__((ext_vector_type(8))) short short8;
typedef __attribute__((ext_vector_type(4))) float f32x4;

__device__ __forceinline__ unsigned short bf16_rhu(float v) {
    return (unsigned short)((__float_as_uint(v) + 0x8000u) >> 16);
}

// we_g[k][f] = LOG2E * sum_d W[h,f,d]*a[h, sel*32+d], k = sel*8 + h
__global__ __launch_bounds__(256) void we_kernel(
    const float* __restrict__ W, const float* __restrict__ a, float* __restrict__ we_g)
{
    const int k = blockIdx.x;            // 0..15
    const int h = k & 7, sel = k >> 3;
    const int f = threadIdx.x;
    const float* wr = W + ((size_t)h * INF + f) * DD;
    const float* av = a + h * 2 * DD + sel * DD;
    float acc = 0.f;
    #pragma unroll
    for (int d = 0; d < DD; ++d) acc += wr[d] * av[d];
    we_g[k * INF + f] = acc * LOG2E;
}

// prep: x -> bf16 (coalesced), W -> wT bf16 [h*32+d][f], exact fp32 e-dots.
// esrc = raw (log2-scaled) src scores; ejE = exp2(ej), ejE5 = exp2(0.2*ej).
// grid 512 x 256
__global__ __launch_bounds__(256) void prep_kernel(
    const float* __restrict__ x, const float* __restrict__ W,
    const float* __restrict__ we_g, unsigned short* __restrict__ xbf,
    unsigned short* __restrict__ wT, float* __restrict__ esrc,
    float* __restrict__ ejE, float* __restrict__ ejE5)
{
    __shared__ __align__(16) float weld[16 * 256];
    const int t = threadIdx.x;
    #pragma unroll
    for (int i = 0; i < 4; ++i)
        *(f32x4*)&weld[i * 1024 + t * 4] = *(const f32x4*)&we_g[i * 1024 + t * 4];
    if (blockIdx.x < 32) {   // W transpose: wT[h*32+d][f]
        #pragma unroll
        for (int r2 = 0; r2 < 8; ++r2) {
            int row = blockIdx.x * 8 + r2;
            int h = row >> 5, d = row & 31;
            wT[row * INF + t] = bf16_rhu(W[((size_t)h * INF + t) * DD + d]);
        }
    }
    __syncthreads();
    const int wv = t >> 6, l = t & 63;
    const int rr = l >> 4, c = l & 15;
    const int gr = blockIdx.x * 16 + wv * 4 + rr;   // 0..8191
    const int b = gr >> 11, n = gr & 2047;
    const float* xr = x + (size_t)gr * INF + c * 16;
    f32x4 xx[4];
    #pragma unroll
    for (int i = 0; i < 4; ++i) xx[i] = *(const f32x4*)&xr[i * 4];
    unsigned pk[8];
    #pragma unroll
    for (int i = 0; i < 8; ++i) {
        unsigned lo = __float_as_uint(xx[i >> 1][(i & 1) * 2]) + 0x8000u;
        unsigned hi = __float_as_uint(xx[i >> 1][(i & 1) * 2 + 1]) + 0x8000u;
        pk[i] = __builtin_amdgcn_perm(hi, lo, 0x07060302u);
    }
    *(uint4*)&xbf[(size_t)gr * INF + c * 16] = *(uint4*)&pk[0];
    *(uint4*)&xbf[(size_t)gr * INF + c * 16 + 8] = *(uint4*)&pk[4];
    #pragma unroll
    for (int k = 0; k < 16; ++k) {
        const float* wk = &weld[k * 256 + c * 16];
        float s = 0.f;
        #pragma unroll
        for (int i = 0; i < 4; ++i) {
            f32x4 w4 = *(const f32x4*)&wk[i * 4];
            s += xx[i][0]*w4[0] + xx[i][1]*w4[1] + xx[i][2]*w4[2] + xx[i][3]*w4[3];
        }
        s += __shfl_xor(s, 1, 64);
        s += __shfl_xor(s, 2, 64);
        s += __shfl_xor(s, 4, 64);
        s += __shfl_xor(s, 8, 64);
        if (c == k) {
            if (k < 8) {
                esrc[(b * 8 + k) * NN + n] = s;
            } else {
                ejE [(b * 8 + (k - 8)) * NN + n] = __builtin_amdgcn_exp2f(s);
                ejE5[(b * 8 + (k - 8)) * NN + n] = __builtin_amdgcn_exp2f(0.2f * s);
            }
        }
    }
}

// wh GEMM: 128 rows x 64 cols (head-pair) x K=256, output whT2[bh][j/8][d][8] bf16
// grid 256 x 512
__global__ __launch_bounds__(512) void wh_kernel(
    const unsigned short* __restrict__ xbf, const unsigned short* __restrict__ wT,
    unsigned short* __restrict__ whT2)
{
    __shared__ __align__(16) unsigned short xb[128 * 264];
    __shared__ __align__(16) unsigned short wb[64 * 264];
    const int t = threadIdx.x;
    const int hp = blockIdx.x & 3, ntile = (blockIdx.x >> 2) & 15, b = blockIdx.x >> 6;
    const int n0 = ntile * 128;
    #pragma unroll
    for (int p = 0; p < 8; ++p) {
        int flat = p * 4096 + t * 8;
        int row = flat >> 8, col = flat & 255;
        *(short8*)&xb[row * 264 + col] =
            *(const short8*)&xbf[((size_t)b * NN + n0 + row) * INF + col];
    }
    #pragma unroll
    for (int p = 0; p < 4; ++p) {
        int flat = p * 4096 + t * 8;
        int cc = flat >> 8, f = flat & 255;
        *(short8*)&wb[cc * 264 + f] = *(const short8*)&wT[(hp * 64 + cc) * INF + f];
    }
    __syncthreads();
    const int w = t >> 6, l = t & 63;
    const int wm = w & 3, wn = w >> 2;
    const int ml = l & 15, q = l >> 4;
    f32x4 acc[2][2] = {};
    const unsigned short* a0p = &xb[(wm * 32 + ml) * 264 + q * 8];
    const unsigned short* a1p = &xb[(wm * 32 + 16 + ml) * 264 + q * 8];
    const unsigned short* b0p = &wb[(wn * 32 + ml) * 264 + q * 8];
    const unsigned short* b1p = &wb[(wn * 32 + 16 + ml) * 264 + q * 8];
    #pragma unroll
    for (int k0 = 0; k0 < INF; k0 += 32) {
        short8 A0 = *(const short8*)&a0p[k0];
        short8 A1 = *(const short8*)&a1p[k0];
        short8 B0 = *(const short8*)&b0p[k0];
        short8 B1 = *(const short8*)&b1p[k0];
        acc[0][0] = __builtin_amdgcn_mfma_f32_16x16x32_bf16(A0, B0, acc[0][0], 0, 0, 0);
        acc[0][1] = __builtin_amdgcn_mfma_f32_16x16x32_bf16(A0, B1, acc[0][1], 0, 0, 0);
        acc[1][0] = __builtin_amdgcn_mfma_f32_16x16x32_bf16(A1, B0, acc[1][0], 0, 0, 0);
        acc[1][1] = __builtin_amdgcn_mfma_f32_16x16x32_bf16(A1, B1, acc[1][1], 0, 0, 0);
    }
    __syncthreads();
    unsigned short* ldsC = xb;   // [64 col][136]
    #pragma unroll
    for (int mt = 0; mt < 2; ++mt)
        #pragma unroll
        for (int nt = 0; nt < 2; ++nt)
            #pragma unroll
            for (int r = 0; r < 4; ++r) {
                int ct = wn * 32 + nt * 16 + ml;
                int rt = wm * 32 + mt * 16 + q * 4 + r;
                ldsC[ct * 136 + rt] = bf16_rhu(acc[mt][nt][r]);
            }
    __syncthreads();
    #pragma unroll
    for (int p = 0; p < 2; ++p) {
        int g = p * 512 + t;
        int d = g & 31, jo = (g >> 5) & 15, h2 = g >> 9;
        short8 vv = *(const short8*)&ldsC[(h2 * 32 + d) * 136 + jo * 8];
        int bh = b * 8 + hp * 2 + h2;
        *(short8*)&whT2[(((size_t)bh * 256 + ntile * 16 + jo) * 32 + d) * 8] = vv;
    }
}

// attn: 512 blocks (b, 16-row i-tile) x 1024 thr; 16 waves = 8 heads x 2 j-halves.
// No exp in hot loop: p = (Ej>Ti) ? Ej*Ei : Ej5*Ei5. adj as ballot bitmask.
__global__ __launch_bounds__(1024, 8) void attn_kernel(
    const int* __restrict__ adj, const unsigned short* __restrict__ whT2,
    const float* __restrict__ esrc, const float* __restrict__ ejE,
    const float* __restrict__ ejE5, float* __restrict__ out)
{
    __shared__ __align__(16) unsigned bits[2][2][16][4];   // [js][dbuf][row][128 bits]
    __shared__ __align__(16) float cmb[8][64][12];
    const int t = threadIdx.x, v = t >> 6, l = t & 63;
    const int h = v & 7, js = v >> 3;
    const int ml = l & 15, q = l >> 4;
    const int it = blockIdx.x & 127, b = blockIdx.x >> 7;
    const int i0 = it * 16;
    const int bh = b * HH + h;

    const float ei  = esrc[bh * NN + i0 + ml];
    const float Ei  = __builtin_amdgcn_exp2f(ei);
    const float Ei5 = __builtin_amdgcn_exp2f(0.2f * ei);
    const float Ti  = __builtin_amdgcn_exp2f(-ei);

    const float* EjP  = ejE  + bh * NN + js * 1024;
    const float* FjP  = ejE5 + bh * NN + js * 1024;
    const unsigned short* whb = whT2 + ((size_t)bh * 256 + js * 128) * 256;

    auto stage = [&](int c2, int buf) {
        #pragma unroll
        for (int u = 0; u < 4; ++u) {
            int uid = h * 4 + u;            // 0..31 within this js group
            int row = uid & 15, half = uid >> 4;
            const int* g = adj + ((size_t)(b * NN + i0 + row)) * NN
                               + js * 1024 + c2 * 128 + half * 64 + l;
            int a0 = g[0];
            unsigned long long m0 = __ballot(a0 != 0);
            if (l == 0)
                *(uint2*)&bits[js][buf][row][half * 2] =
                    make_uint2((unsigned)m0, (unsigned)(m0 >> 32));
        }
    };

    const short8 ones = {0x3F80, 0x3F80, 0x3F80, 0x3F80, 0x3F80, 0x3F80, 0x3F80, 0x3F80};
    f32x4 acc0 = {}, acc1 = {}, accD = {};

    stage(0, 0);
    for (int c = 0; c < 8; ++c) {
        __syncthreads();
        if (c < 7) stage(c + 1, (c + 1) & 1);
        const int buf = c & 1;
        unsigned wa[4];
        *(uint4*)wa = *(const uint4*)&bits[js][buf][ml][0];
        const float* ejc = EjP + c * 128;
        const float* fjc = FjP + c * 128;
        #pragma unroll
        for (int k = 0; k < 4; ++k) {
            const int jb = k * 32 + q * 8;
            f32x4 EA = *(const f32x4*)&ejc[jb];
            f32x4 EB = *(const f32x4*)&ejc[jb + 4];
            f32x4 FA = *(const f32x4*)&fjc[jb];
            f32x4 FB = *(const f32x4*)&fjc[jb + 4];
            const unsigned short* wp = whb + (size_t)(c * 16 + k * 4 + q) * 256;
            short8 B0 = *(const short8*)&wp[ml * 8];
            short8 B1 = *(const short8*)&wp[(16 + ml) * 8];
            unsigned st = wa[k] >> (q * 8);
            union { unsigned u[4]; short8 s; } f0;
            #pragma unroll
            for (int pp = 0; pp < 4; ++pp) {
                float eA = (pp < 2) ? EA[2 * pp]     : EB[2 * pp - 4];
                float eB = (pp < 2) ? EA[2 * pp + 1] : EB[2 * pp - 3];
                float fA = (pp < 2) ? FA[2 * pp]     : FB[2 * pp - 4];
                float fB = (pp < 2) ? FA[2 * pp + 1] : FB[2 * pp - 3];
                float pA = (eA > Ti) ? eA * Ei : fA * Ei5;
                float pB = (eB > Ti) ? eB * Ei : fB * Ei5;
                unsigned mA = (unsigned)__builtin_amdgcn_sbfe(st, 2 * pp, 1);
                unsigned mB = (unsigned)__builtin_amdgcn_sbfe(st, 2 * pp + 1, 1);
                unsigned ra = (__float_as_uint(pA) + 0x8000u) & mA;
                unsigned rb = (__float_as_uint(pB) + 0x8000u) & mB;
                f0.u[pp] = __builtin_amdgcn_perm(rb, ra, 0x07060302u);
            }
            acc0 = __builtin_amdgcn_mfma_f32_16x16x32_bf16(f0.s, B0, acc0, 0, 0, 0);
            acc1 = __builtin_amdgcn_mfma_f32_16x16x32_bf16(f0.s, B1, acc1, 0, 0, 0);
            accD = __builtin_amdgcn_mfma_f32_16x16x32_bf16(f0.s, ones, accD, 0, 0, 0);
        }
    }

    float* myc = &cmb[h][l][0];
    if (js == 1) {
        *(f32x4*)&myc[0] = acc0;
        *(f32x4*)&myc[4] = acc1;
        *(f32x4*)&myc[8] = accD;
    }
    __syncthreads();
    if (js == 0) {
        f32x4 o0 = *(const f32x4*)&myc[0];
        f32x4 o1 = *(const f32x4*)&myc[4];
        f32x4 oD = *(const f32x4*)&myc[8];
        #pragma unroll
        for (int r = 0; r < 4; ++r) {
            int ir = i0 + q * 4 + r;
            float inv = 1.0f / (accD[r] + oD[r]);
            size_t ba = ((size_t)(b * NN + ir)) * (HH * DD) + h * DD;
            out[ba + ml]      = (acc0[r] + o0[r]) * inv;
            out[ba + 16 + ml] = (acc1[r] + o1[r]) * inv;
        }
    }
}

extern "C" void kernel_launch(void* const* d_in, const int* in_sizes, int n_in,
                              void* d_out, int out_size, void* d_ws, size_t ws_size,
                              hipStream_t stream) {
    (void)in_sizes; (void)n_in; (void)out_size; (void)ws_size;
    const float* x   = (const float*)d_in[0];
    const int*   adj = (const int*)d_in[1];
    const float* W   = (const float*)d_in[2];
    const float* a   = (const float*)d_in[3];
    float* out = (float*)d_out;

    char* ws = (char*)d_ws;
    unsigned short* whT2 = (unsigned short*)ws;                         // 4 MB
    unsigned short* xbf  = (unsigned short*)(ws + (4u << 20));          // 4 MB
    unsigned short* wT   = (unsigned short*)(ws + (8u << 20));          // 128 KB
    float* esrc = (float*)(ws + (8u << 20) + (128u << 10));             // 256 KB
    float* ejE  = esrc + BB * HH * NN;                                  // 256 KB
    float* ejE5 = ejE + BB * HH * NN;                                   // 256 KB
    float* we_g = ejE5 + BB * HH * NN;                                  // 16 KB

    we_kernel<<<dim3(16), dim3(256), 0, stream>>>(W, a, we_g);
    prep_kernel<<<dim3(512), dim3(256), 0, stream>>>(x, W, we_g, xbf, wT, esrc, ejE, ejE5);
    wh_kernel<<<dim3(256), dim3(512), 0, stream>>>(xbf, wT, whT2);
    attn_kernel<<<dim3(512), dim3(1024), 0, stream>>>(adj, whT2, esrc, ejE, ejE5, out);
}